// Round 3
// baseline (237.370 us; speedup 1.0000x reference)
//
#include <hip/hip_runtime.h>
#include <cstddef>

// Problem constants
constexpr int Bn  = 16;    // batch
constexpr int CIc = 32;    // in channels
constexpr int COc = 32;    // out channels
constexpr int Kc  = 16;    // kernel width
constexpr int IN  = 8192;  // input length
constexpr int OUTL = 8176; // output length = IN - K

// Tiling
constexpr int O_B  = 16;   // o-positions per block (8176/16 = 511 exact)
constexpr int CCH  = 8;    // channels per cg-chunk in inner loop
constexpr int NPOS = 32;   // staged x positions (31 needed; 32 for shift-only math, in-bounds since o0+31 <= 8191)
constexpr int BST  = 20;   // padded batch stride in LDS floats (bank stride 20 -> <=2-way, free)

// LDS: xs[2cg][8cc][32p][20b] floats = 40960 B, aliased with red[8dg][4jd][16og][20b] = 40960 B
constexpr int SMEM_FLOATS = 10240;

__global__ __launch_bounds__(256, 2)
void conv1d_cppn_kernel(const float* __restrict__ x, const float* __restrict__ w,
                        const float* __restrict__ bias, float* __restrict__ out) {
    __shared__ float smem[SMEM_FLOATS];
    float (*xs)[CCH][NPOS][BST] = reinterpret_cast<float (*)[CCH][NPOS][BST]>(smem);
    float (*red)[4][O_B][BST]   = reinterpret_cast<float (*)[4][O_B][BST]>(smem);

    const int tid = threadIdx.x;
    const int og = tid & 15;          // o within tile (fast -> coalesced w loads)
    const int dg = (tid >> 4) & 7;    // 8 d-groups x 4 d each = all 32 d
    const int cg = tid >> 7;          // c-split: cg0 -> c 0..15, cg1 -> c 16..31 (disjoint w!)
    const int o0 = blockIdx.x * O_B;
    const int o  = o0 + og;
    const int dbase = dg * 4;

    float acc[4][16];
#pragma unroll
    for (int i = 0; i < 4; ++i)
#pragma unroll
        for (int j = 0; j < 16; ++j) acc[i][j] = 0.f;

    for (int it = 0; it < 2; ++it) {
        __syncthreads();
        // Stage x channels it*16 .. it*16+15 for both cg halves. p fastest -> coalesced.
        // 16ch * 16b * 32p = 8192 elems, 32 per thread; shift/mask indexing only.
        for (int idx = tid; idx < 16 * Bn * NPOS; idx += 256) {
            const int p  = idx & 31;
            const int t  = idx >> 5;
            const int b  = t & 15;
            const int cl = t >> 4;     // 0..15 local channel
            xs[cl >> 3][cl & 7][p][b] = x[((size_t)b * CIc + (it * 16 + cl)) * IN + o0 + p];
        }
        __syncthreads();

        for (int cc = 0; cc < CCH; ++cc) {
            const int c = it * 16 + cg * 8 + cc;
            // w[d, c, o, 0..16) for this thread's 4 d's: 64B contiguous each, loaded ONCE grid-wide.
            float wreg[4][16];
#pragma unroll
            for (int jd = 0; jd < 4; ++jd) {
                const float4* wp = reinterpret_cast<const float4*>(
                    w + (((size_t)(dbase + jd) * CIc + c) * OUTL + o) * Kc);
#pragma unroll
                for (int q = 0; q < 4; ++q) {
                    const float4 v = wp[q];
                    wreg[jd][q * 4 + 0] = v.x;
                    wreg[jd][q * 4 + 1] = v.y;
                    wreg[jd][q * 4 + 2] = v.z;
                    wreg[jd][q * 4 + 3] = v.w;
                }
            }
#pragma unroll
            for (int k = 0; k < Kc; ++k) {
                const float* xrow = &xs[cg][cc][og + k][0];
                float xv[16];
                *reinterpret_cast<float4*>(&xv[0])  = *reinterpret_cast<const float4*>(xrow);
                *reinterpret_cast<float4*>(&xv[4])  = *reinterpret_cast<const float4*>(xrow + 4);
                *reinterpret_cast<float4*>(&xv[8])  = *reinterpret_cast<const float4*>(xrow + 8);
                *reinterpret_cast<float4*>(&xv[12]) = *reinterpret_cast<const float4*>(xrow + 12);
#pragma unroll
                for (int jd = 0; jd < 4; ++jd) {
                    const float wk = wreg[jd][k];
#pragma unroll
                    for (int jb = 0; jb < 16; ++jb) {
                        acc[jd][jb] += wk * xv[jb];
                    }
                }
            }
        }
    }

    // Combine cg partials through LDS (aliased with xs; dead after last FMA + barrier).
    __syncthreads();
    if (cg == 1) {
#pragma unroll
        for (int jd = 0; jd < 4; ++jd) {
            float* row = &red[dg][jd][og][0];
#pragma unroll
            for (int q = 0; q < 4; ++q) {
                *reinterpret_cast<float4*>(row + q * 4) =
                    make_float4(acc[jd][q * 4 + 0], acc[jd][q * 4 + 1],
                                acc[jd][q * 4 + 2], acc[jd][q * 4 + 3]);
            }
        }
    }
    __syncthreads();
    if (cg == 0) {
#pragma unroll
        for (int jd = 0; jd < 4; ++jd) {
            const float bv = bias[dbase + jd];
            const float* row = &red[dg][jd][og][0];
#pragma unroll
            for (int jb = 0; jb < 16; ++jb) {
                float v = acc[jd][jb] + row[jb] + bv;
                out[((size_t)jb * COc + (dbase + jd)) * OUTL + o] = v > 0.f ? v : 0.f;
            }
        }
    }
}

extern "C" void kernel_launch(void* const* d_in, const int* in_sizes, int n_in,
                              void* d_out, int out_size, void* d_ws, size_t ws_size,
                              hipStream_t stream) {
    const float* x    = (const float*)d_in[0];
    const float* w    = (const float*)d_in[1];
    const float* bias = (const float*)d_in[2];
    float* out        = (float*)d_out;

    dim3 grid(OUTL / O_B);  // 511
    dim3 block(256);
    hipLaunchKernelGGL(conv1d_cppn_kernel, grid, block, 0, stream, x, w, bias, out);
}